// Round 3
// baseline (184.302 us; speedup 1.0000x reference)
//
#include <hip/hip_runtime.h>

// MeanConv: out = mask * (1/7) * sum_{k in 3,5,..,15} boxmean_k(x), edge padding.
// Per-tile 2D integral image in LDS; each box sum = 4-corner difference.
// All phases fully parallel:
//   P1: stage+row-prefix fused — 20-float row segments in registers,
//       4-lane __shfl_up fixup, write prefixed rows to LDS. No serial walk.
//   P2: column prefix — 4 segments of <=20 rows per column, register prefix
//       + 4-lane shuffle fixup.
//   P3: 16 px/thread (4 col-groups x 64 rows). Per scale, the cl-run and
//       cr-run of 16 corners merge into ONE contiguous span of 17+2p words
//       per row; load span, form row-difference D once, then 16 (sub+fma).
//       448 -> 350 LDS words/thread vs the 8-px/thread version.
// Only 2 barriers. LDS 26.9 KB.

#define TILE   64
#define HALO   7
#define LHX    8            // left halo (8 for float4 alignment)
#define NCOL   80           // staged cols: c0-8 .. c0+71
#define NROW   78           // staged rows: r0-7 .. r0+70
#define PSTR   83           // odd; 19 mod 32 -> conflict-free pixel/col patterns
#define PROWSA 81           // rows 0..78 used + 2 slack (safe predicated reads)
#define HH     4096
#define WW     4096

__global__ __launch_bounds__(256) void meanconv_kernel(
    const float* __restrict__ x, const float* __restrict__ mask,
    float* __restrict__ out)
{
    __shared__ float P[PROWSA * PSTR];   // 81*83*4 = 26892 B
    const int tid = threadIdx.x;
    const int c0  = blockIdx.x * TILE;
    const int r0  = blockIdx.y * TILE;

    // zero row 0 (cols 0..80); rows 1..78 written below, no race
    if (tid < 81) P[tid] = 0.0f;

    const bool xint = (c0 >= LHX) && (c0 - LHX + NCOL <= WW);

    // ---- phase 1: fused global stage + row-wise inclusive prefix ----
    for (int idx = tid; idx < NROW * 4; idx += 256) {
        const int lr  = idx >> 2;        // staged row 0..77
        const int s   = idx & 3;         // 20-col segment within the row
        const int gr  = min(max(r0 + lr - HALO, 0), HH - 1);
        const int gc0 = c0 - LHX + 20 * s;
        float v[20];
        if (xint) {
            const float* src = &x[(size_t)gr * WW + gc0];
            #pragma unroll
            for (int q = 0; q < 5; ++q) {
                const float4 t = *(const float4*)(src + 4 * q);
                v[4*q+0] = t.x; v[4*q+1] = t.y; v[4*q+2] = t.z; v[4*q+3] = t.w;
            }
        } else {
            #pragma unroll
            for (int i = 0; i < 20; ++i) {
                const int gc = min(max(gc0 + i, 0), WW - 1);
                v[i] = x[(size_t)gr * WW + gc];
            }
        }
        #pragma unroll
        for (int i = 1; i < 20; ++i) v[i] += v[i - 1];
        // 4-lane (one row) exclusive prefix of segment totals
        const float tot = v[19];
        float sum = tot;
        float u = __shfl_up(sum, 1, 4); if (s >= 1) sum += u;
        u       = __shfl_up(sum, 2, 4); if (s >= 2) sum += u;
        const float off = sum - tot;
        float* dst = &P[(lr + 1) * PSTR + 1 + 20 * s];
        #pragma unroll
        for (int i = 0; i < 20; ++i) dst[i] = v[i] + off;
    }
    __syncthreads();

    // ---- phase 2: column-wise inclusive prefix over rows 1..78 ----
    for (int idx = tid; idx < 80 * 4; idx += 256) {
        const int c  = (idx >> 2) + 1;   // col 1..80
        const int s  = idx & 3;          // row segment (20,20,20,18)
        const int rs = 1 + 20 * s;
        float v[20];
        float run = 0.0f;
        #pragma unroll
        for (int i = 0; i < 20; ++i) {
            const int r = rs + i;
            float t = P[r * PSTR + c];   // rows 79,80 are in-bounds slack
            t = (r < 79) ? t : 0.0f;     // zero out slack garbage
            run += t; v[i] = run;
        }
        const float tot = run;
        float sum = tot;
        float u = __shfl_up(sum, 1, 4); if (s >= 1) sum += u;
        u       = __shfl_up(sum, 2, 4); if (s >= 2) sum += u;
        const float off = sum - tot;
        #pragma unroll
        for (int i = 0; i < 20; ++i) {
            const int r = rs + i;
            if (r < 79) P[r * PSTR + c] = v[i] + off;
        }
    }
    __syncthreads();
    // P[a][b] = sum of staged[row < a][col < b].

    // ---- phase 3: 16 consecutive-x pixels per thread, one row each ----
    // thread (g, ty): g = column group (4 groups of 16 px), ty = tile row.
    const int g  = tid & 3;
    const int ty = tid >> 2;             // 0..63
    const int B0 = 16 * g;
    const int A  = ty + HALO;            // staged row of the pixel
    float a[16];
    #pragma unroll
    for (int i = 0; i < 16; ++i) a[i] = 0.0f;

    #pragma unroll
    for (int p = 1; p <= 7; ++p) {
        const int   k = 2 * p + 1;
        const float w = 1.0f / (7.0f * (float)(k * k));
        const int   W = 17 + 2 * p;      // span: cols [B0+LHX-p, B0+LHX+p+16]
        const float* rT = &P[(A - p)     * PSTR + B0 + LHX - p];
        const float* rB = &P[(A + p + 1) * PSTR + B0 + LHX - p];
        float D[31];
        #pragma unroll
        for (int q = 0; q < W; ++q) D[q] = rB[q] - rT[q];
        // corner diff: (rB-rT)[cr+i] - (rB-rT)[cl+i]; cl=span[0], cr=span[k]
        #pragma unroll
        for (int i = 0; i < 16; ++i)
            a[i] += w * (D[k + i] - D[i]);
    }

    const int gr = r0 + ty, gc = c0 + B0;
    const float* mrow = &mask[(size_t)gr * WW + gc];
    float*       orow = &out[(size_t)gr * WW + gc];
    #pragma unroll
    for (int q = 0; q < 4; ++q) {
        const float4 m = *(const float4*)(mrow + 4 * q);
        float4 o;
        o.x = a[4*q+0] * m.x;
        o.y = a[4*q+1] * m.y;
        o.z = a[4*q+2] * m.z;
        o.w = a[4*q+3] * m.w;
        *(float4*)(orow + 4 * q) = o;
    }
}

extern "C" void kernel_launch(void* const* d_in, const int* in_sizes, int n_in,
                              void* d_out, int out_size, void* d_ws, size_t ws_size,
                              hipStream_t stream) {
    const float* x    = (const float*)d_in[0];
    const float* mask = (const float*)d_in[1];
    float*       out  = (float*)d_out;
    dim3 grid(WW / TILE, HH / TILE);
    meanconv_kernel<<<grid, 256, 0, stream>>>(x, mask, out);
}